// Round 6
// baseline (353.879 us; speedup 1.0000x reference)
//
#include <hip/hip_runtime.h>
#include <hip/hip_bf16.h>

#define SLOPE 0.2f
#define DH 256
#define DE 128
#define CAP 128   // max edges per node slot; Binomial(320k,1e-4) max ~56, 128 is ~17 sigma

typedef __bf16 bf16_t;
typedef bf16_t bf16x8 __attribute__((ext_vector_type(8)));
typedef bf16_t bf16x4 __attribute__((ext_vector_type(4)));
typedef float f32x4 __attribute__((ext_vector_type(4)));

__device__ __forceinline__ float lrelu(float x) { return x > 0.f ? x : SLOPE * x; }

// ---------------------------------------------------------------------------
// Cast + transpose weights to bf16: wT[n][k] = wW[k][n]  (256x256)
//                                   ewT[n][k] = ewW[k][n] (256x128)
// Also zeroes cursor[0..N] (cursor[N] doubles as the edge-chunk dispenser).
// ---------------------------------------------------------------------------
__global__ void prep_weights(const float* __restrict__ wW, const float* __restrict__ ewW,
                             bf16_t* __restrict__ wT, bf16_t* __restrict__ ewT,
                             int* __restrict__ cursor, int N) {
    int n = blockIdx.x;   // 0..255 (output col of original)
    int k = threadIdx.x;  // 0..255
    wT[n * 256 + k] = (bf16_t)wW[k * 256 + n];
    if (k < 128) ewT[n * 128 + k] = (bf16_t)ewW[k * 256 + n];
    int idx = blockIdx.x * 256 + threadIdx.x;
    if (idx <= N) cursor[idx] = 0;   // includes dispenser word at cursor[N]
}

// ---------------------------------------------------------------------------
// Fused projections with WORK-STEALING edge loop.
// Race-free: s1 cancels by softmax shift-invariance; s2[j] deferred to
// aggregate -> edge work depends only on prep outputs.
//
// Blocks [0, NB_NODE) first run the node path (128 rows x 256 cols, 8 waves):
//   h = lrelu(nf @ wW + wb)  [bf16];  s2 = h . aW[256:512]
// then ALL 512 blocks re-stage B/EW and pull 16-edge chunks from a global
// atomic dispenser (batches of 4 per wave) — no idle block slots, no static
// tail imbalance:
//   s3 = lrelu(ef @ ewW + ewb) . aW[512:768] + a_b
//   pairs[tgt*CAP + cursor[tgt]++] = { nbr, s3 }
// LDS union: node 69632 B, edge 71680 B -> 2 blocks/CU; VGPR <=128 via
// launch_bounds(512,4).
// ---------------------------------------------------------------------------
__global__ __launch_bounds__(512, 4) void proj_fused(
        const float* __restrict__ nf, const bf16_t* __restrict__ wT,
        const float* __restrict__ wb, const float* __restrict__ aW,
        bf16_t* __restrict__ h, float* __restrict__ s2,
        const float* __restrict__ ef, const bf16_t* __restrict__ ewT,
        const float* __restrict__ eb, const float* __restrict__ ab,
        const int* __restrict__ tgt, const int* __restrict__ nbr,
        int* __restrict__ cursor, int* __restrict__ disp,
        float2* __restrict__ pairs,
        int N, int E, int NB_NODE) {
    __shared__ __align__(16) unsigned char smem[71680];

    const int tid = threadIdx.x;
    const int wave = tid >> 6, lane = tid & 63;
    const int q = lane >> 4, l = lane & 15;

    if (blockIdx.x < NB_NODE) {
        // ------------------------- node path -------------------------
        bf16_t (*A)[264] = (bf16_t(*)[264])smem;                 // 67584 B
        float (*p2)[64] = (float(*)[64])(smem + 67584);          // 2048 B

        const int m0 = blockIdx.x * 128;
        for (int i = tid; i < 128 * 64; i += 512) {
            int r = i >> 6;
            int c4 = (i & 63) * 4;
            int row = m0 + r;
            if (row >= N) row = N - 1;
            const float4 v = *(const float4*)(nf + (size_t)row * 256 + c4);
            bf16_t* dst = &A[r][c4];
            dst[0] = (bf16_t)v.x; dst[1] = (bf16_t)v.y; dst[2] = (bf16_t)v.z; dst[3] = (bf16_t)v.w;
        }
        __syncthreads();

        const int rh = wave >> 2;   // row half (0/1)
        const int wc = wave & 3;    // col group

        f32x4 acc[4][4];
        for (int rt = 0; rt < 4; rt++)
            for (int ct = 0; ct < 4; ct++)
                acc[rt][ct] = (f32x4){0.f, 0.f, 0.f, 0.f};

        for (int kc = 0; kc < 8; kc++) {
            bf16x8 bf[4];
            for (int ct = 0; ct < 4; ct++) {
                int n = wc * 64 + ct * 16 + l;
                bf[ct] = *(const bf16x8*)(wT + (size_t)n * 256 + kc * 32 + q * 8);
            }
            bf16x8 af[4];
            for (int rt = 0; rt < 4; rt++)
                af[rt] = *(const bf16x8*)(&A[rh * 64 + rt * 16 + l][kc * 32 + q * 8]);
            for (int rt = 0; rt < 4; rt++)
                for (int ct = 0; ct < 4; ct++)
                    acc[rt][ct] = __builtin_amdgcn_mfma_f32_16x16x32_bf16(af[rt], bf[ct], acc[rt][ct], 0, 0, 0);
        }

        float bias[4], w2[4];
        for (int ct = 0; ct < 4; ct++) {
            int n = wc * 64 + ct * 16 + l;
            bias[ct] = wb[n];
            w2[ct] = aW[256 + n];
        }
        for (int rt = 0; rt < 4; rt++) {
            float rs2[4] = {0.f, 0.f, 0.f, 0.f};
            for (int ct = 0; ct < 4; ct++) {
                int col = wc * 64 + ct * 16 + l;
                for (int r = 0; r < 4; r++) {
                    float p = lrelu(acc[rt][ct][r] + bias[ct]);
                    int row = m0 + rh * 64 + rt * 16 + q * 4 + r;
                    if (row < N) h[(size_t)row * 256 + col] = (bf16_t)p;
                    rs2[r] += p * w2[ct];
                }
            }
            for (int off = 1; off < 16; off <<= 1)
                for (int r = 0; r < 4; r++)
                    rs2[r] += __shfl_xor(rs2[r], off, 64);
            if (l == 0)
                for (int r = 0; r < 4; r++)
                    p2[wave][rt * 16 + q * 4 + r] = rs2[r];
        }
        __syncthreads();
        if (tid < 128 && m0 + tid < N) {
            int rh2 = tid >> 6, t = tid & 63;
            s2[m0 + tid] = p2[rh2 * 4 + 0][t] + p2[rh2 * 4 + 1][t] + p2[rh2 * 4 + 2][t] + p2[rh2 * 4 + 3][t];
        }
        __syncthreads();   // p2 fully consumed before LDS is re-staged as B
    }

    // ---------------- edge path: ALL blocks, work-stealing ----------------
    bf16_t (*B)[136] = (bf16_t(*)[136])smem;                     // 69632 B
    float2* EW = (float2*)(smem + 69632);                        // 2048 B

    {
        int col = tid >> 1, half = tid & 1;
        const bf16x8* src = (const bf16x8*)(ewT + (size_t)col * 128 + half * 64);
        bf16_t* dst = &B[col][half * 64];
#pragma unroll
        for (int i = 0; i < 8; i++)
            *(bf16x8*)(dst + i * 8) = src[i];
    }
    if (tid < 256) EW[tid] = make_float2(eb[tid], aW[512 + tid]);
    const float ab0 = ab[0];
    __syncthreads();

    const int nchunks = (E + 15) >> 4;

    // per-wave dispenser: grab 4 sequential 16-edge chunks per atomic
    int base = 0;
    if (lane == 0) base = atomicAdd(disp, 4);
    base = __builtin_amdgcn_readfirstlane(base);
    int k = 0;
    int c = base;

    f32x4 a0[4], a1[4];
    if (c < nchunks) {
        int row = c * 16 + l;
        if (row >= E) row = E - 1;
        const float* arow = ef + (size_t)row * 128 + q * 8;
#pragma unroll
        for (int kc = 0; kc < 4; kc++) {
            a0[kc] = *(const f32x4*)(arow + kc * 32);
            a1[kc] = *(const f32x4*)(arow + kc * 32 + 4);
        }
    }

    while (c < nchunks) {
        const int e0 = c * 16;

        int cn;
        if (k < 3) {
            cn = c + 1; ++k;
        } else {
            if (lane == 0) base = atomicAdd(disp, 4);
            base = __builtin_amdgcn_readfirstlane(base);
            cn = base; k = 0;
        }

        bf16x8 af[4];
#pragma unroll
        for (int kc = 0; kc < 4; kc++) {
            af[kc][0] = (bf16_t)a0[kc][0]; af[kc][1] = (bf16_t)a0[kc][1];
            af[kc][2] = (bf16_t)a0[kc][2]; af[kc][3] = (bf16_t)a0[kc][3];
            af[kc][4] = (bf16_t)a1[kc][0]; af[kc][5] = (bf16_t)a1[kc][1];
            af[kc][6] = (bf16_t)a1[kc][2]; af[kc][7] = (bf16_t)a1[kc][3];
        }
        if (cn < nchunks) {
            int row = cn * 16 + l;
            if (row >= E) row = E - 1;
            const float* arow = ef + (size_t)row * 128 + q * 8;
#pragma unroll
            for (int kc = 0; kc < 4; kc++) {
                a0[kc] = *(const f32x4*)(arow + kc * 32);
                a1[kc] = *(const f32x4*)(arow + kc * 32 + 4);
            }
        }

        float rs0 = 0.f, rs1 = 0.f, rs2 = 0.f, rs3 = 0.f;
#pragma unroll 1
        for (int half = 0; half < 2; half++) {
            f32x4 acc[8];
#pragma unroll
            for (int t = 0; t < 8; t++) acc[t] = (f32x4){0.f, 0.f, 0.f, 0.f};
            __builtin_amdgcn_s_setprio(1);
#pragma unroll
            for (int kc = 0; kc < 4; kc++) {
#pragma unroll
                for (int t = 0; t < 8; t++) {
                    int ct = half * 8 + t;
                    bf16x8 bf = *(const bf16x8*)(&B[ct * 16 + l][kc * 32 + q * 8]);
                    acc[t] = __builtin_amdgcn_mfma_f32_16x16x32_bf16(af[kc], bf, acc[t], 0, 0, 0);
                }
            }
            __builtin_amdgcn_s_setprio(0);
#pragma unroll
            for (int t = 0; t < 8; t++) {
                int ct = half * 8 + t;
                float2 bw = EW[ct * 16 + l];
                rs0 += lrelu(acc[t][0] + bw.x) * bw.y;
                rs1 += lrelu(acc[t][1] + bw.x) * bw.y;
                rs2 += lrelu(acc[t][2] + bw.x) * bw.y;
                rs3 += lrelu(acc[t][3] + bw.x) * bw.y;
            }
        }
#pragma unroll
        for (int off = 1; off < 16; off <<= 1) {
            rs0 += __shfl_xor(rs0, off, 64);
            rs1 += __shfl_xor(rs1, off, 64);
            rs2 += __shfl_xor(rs2, off, 64);
            rs3 += __shfl_xor(rs3, off, 64);
        }
        // fused fill: lanes l<4 each own edge e0 + q*4 + l. pairs = {nbr, s3}
        if (l < 4) {
            int e = e0 + q * 4 + l;
            if (e < E) {
                float rsv = (l == 0) ? rs0 : (l == 1) ? rs1 : (l == 2) ? rs2 : rs3;
                int t = tgt[e];
                int j = nbr[e];
                int p = atomicAdd(&cursor[t], 1);
                if (p < CAP) {
                    float2 pr;
                    pr.x = __int_as_float(j);
                    pr.y = rsv + ab0;
                    pairs[(size_t)t * CAP + p] = pr;
                }
            }
        }
        c = cn;
    }
}

// ---------------------------------------------------------------------------
// Aggregate: one WAVE per node. Pairs {j, s3} preloaded into 2 regs/lane
// (coalesced); logit = s3 + s2[j] built in-register (s2 gather: 2 per lane,
// 40 KB L2-hot table). Max and exp-sum via butterfly shuffles; gather loop
// broadcasts {j, alpha} from registers via __shfl.
// ---------------------------------------------------------------------------
__global__ __launch_bounds__(256) void aggregate(const int* __restrict__ cursor,
                                                 const float2* __restrict__ pairs,
                                                 const float* __restrict__ s2,
                                                 const bf16_t* __restrict__ h,
                                                 float* __restrict__ out, int N) {
    const int wave = threadIdx.x >> 6, lane = threadIdx.x & 63;
    const int n = blockIdx.x * 4 + wave;
    if (n >= N) return;

    int deg = __builtin_amdgcn_readfirstlane(cursor[n]);
    if (deg > CAP) deg = CAP;
    const float2* pp = pairs + (size_t)n * CAP;

    // preload up to 2 pairs per lane (coalesced 512B loads) + s2[j] fold-in
    float2 pr0 = make_float2(0.f, 0.f);
    float2 pr1 = make_float2(0.f, 0.f);
    if (lane < deg) pr0 = pp[lane];
    if (lane + 64 < deg) pr1 = pp[lane + 64];
    float lg0 = (lane < deg) ? pr0.y + s2[__float_as_int(pr0.x)] : -1e30f;
    float lg1 = (lane + 64 < deg) ? pr1.y + s2[__float_as_int(pr1.x)] : -1e30f;

    // in-register segment max
    float m = fmaxf(lg0, lg1);
#pragma unroll
    for (int off = 32; off > 0; off >>= 1) m = fmaxf(m, __shfl_xor(m, off, 64));

    // in-register exp + sum
    float ex0 = (lane < deg) ? expf(lg0 - m) : 0.f;
    float ex1 = (lane + 64 < deg) ? expf(lg1 - m) : 0.f;
    float s = ex0 + ex1;
#pragma unroll
    for (int off = 32; off > 0; off >>= 1) s += __shfl_xor(s, off, 64);
    const float inv = (deg > 0 && s > 0.f) ? 1.0f / s : 0.f;

    // gather: out[n][lane*4..+4) = sum_i alpha_i * h[j_i][lane*4..+4)
    f32x4 acc = (f32x4){0.f, 0.f, 0.f, 0.f};
    const bf16_t* hf = h + lane * 4;
    const int d0 = deg < 64 ? deg : 64;
#pragma unroll 4
    for (int i = 0; i < d0; i++) {
        float a = __shfl(ex0, i, 64);
        int j = __float_as_int(__shfl(pr0.x, i, 64));
        bf16x4 v = *(const bf16x4*)(hf + (size_t)j * 256);
        acc[0] += a * (float)v[0];
        acc[1] += a * (float)v[1];
        acc[2] += a * (float)v[2];
        acc[3] += a * (float)v[3];
    }
#pragma unroll 4
    for (int i = 64; i < deg; i++) {
        float a = __shfl(ex1, i - 64, 64);
        int j = __float_as_int(__shfl(pr1.x, i - 64, 64));
        bf16x4 v = *(const bf16x4*)(hf + (size_t)j * 256);
        acc[0] += a * (float)v[0];
        acc[1] += a * (float)v[1];
        acc[2] += a * (float)v[2];
        acc[3] += a * (float)v[3];
    }
    float4 o;
    o.x = lrelu(acc[0] * inv);
    o.y = lrelu(acc[1] * inv);
    o.z = lrelu(acc[2] * inv);
    o.w = lrelu(acc[3] * inv);
    *(float4*)(out + (size_t)n * 256 + lane * 4) = o;
}

// ---------------------------------------------------------------------------
extern "C" void kernel_launch(void* const* d_in, const int* in_sizes, int n_in,
                              void* d_out, int out_size, void* d_ws, size_t ws_size,
                              hipStream_t stream) {
    const float* nf  = (const float*)d_in[0];
    const float* ef  = (const float*)d_in[1];
    const int*  eidx = (const int*)d_in[2];
    const float* wW  = (const float*)d_in[3];
    const float* wb  = (const float*)d_in[4];
    const float* ewW = (const float*)d_in[5];
    const float* ewb = (const float*)d_in[6];
    const float* aW  = (const float*)d_in[7];
    const float* ab  = (const float*)d_in[8];
    float* out = (float*)d_out;

    const int N = in_sizes[0] / DH;   // 10000
    const int E = in_sizes[1] / DE;   // 320000
    const int* tgt = eidx;
    const int* nbr = eidx + E;

    char* ws = (char*)d_ws;
    size_t off = 0;
    auto alloc = [&](size_t bytes) -> void* {
        void* p = ws + off;
        off += (bytes + 255) & ~(size_t)255;
        return p;
    };
    bf16_t* wT      = (bf16_t*)alloc((size_t)256 * 256 * 2);
    bf16_t* ewT     = (bf16_t*)alloc((size_t)256 * 128 * 2);
    bf16_t* h       = (bf16_t*)alloc((size_t)N * 256 * 2);
    float*  s2      = (float*)alloc((size_t)N * 4);
    int*    cursor  = (int*)alloc((size_t)(N + 1) * 4);   // [N] = chunk dispenser
    float2* pairs   = (float2*)alloc((size_t)N * CAP * 8);
    int*    disp    = cursor + N;

    prep_weights<<<256, 256, 0, stream>>>(wW, ewW, wT, ewT, cursor, N);

    const int NB_NODE = (N + 127) / 128;   // 79
    proj_fused<<<512, 512, 0, stream>>>(
        nf, wT, wb, aW, h, s2,
        ef, ewT, ewb, ab, tgt, nbr, cursor, disp, pairs,
        N, E, NB_NODE);

    aggregate<<<(N + 3) / 4, 256, 0, stream>>>(cursor, pairs, s2, h, out, N);
}

// Round 7
// 299.933 us; speedup vs baseline: 1.1799x; 1.1799x over previous
//
#include <hip/hip_runtime.h>
#include <hip/hip_bf16.h>

#define SLOPE 0.2f
#define DH 256
#define DE 128
#define CAP 128   // max edges per node slot; Binomial(320k,1e-4) max ~56, 128 is ~17 sigma

typedef __bf16 bf16_t;
typedef bf16_t bf16x8 __attribute__((ext_vector_type(8)));
typedef bf16_t bf16x4 __attribute__((ext_vector_type(4)));
typedef float f32x4 __attribute__((ext_vector_type(4)));

__device__ __forceinline__ float lrelu(float x) { return x > 0.f ? x : SLOPE * x; }

// ---------------------------------------------------------------------------
// Cast + transpose weights to bf16: wT[n][k] = wW[k][n]  (256x256)
//                                   ewT[n][k] = ewW[k][n] (256x128)
// Also zeroes the per-node edge-slot cursor.
// ---------------------------------------------------------------------------
__global__ void prep_weights(const float* __restrict__ wW, const float* __restrict__ ewW,
                             bf16_t* __restrict__ wT, bf16_t* __restrict__ ewT,
                             int* __restrict__ cursor, int N) {
    int n = blockIdx.x;   // 0..255 (output col of original)
    int k = threadIdx.x;  // 0..255
    wT[n * 256 + k] = (bf16_t)wW[k * 256 + n];
    if (k < 128) ewT[n * 128 + k] = (bf16_t)ewW[k * 256 + n];
    int idx = blockIdx.x * 256 + threadIdx.x;
    if (idx < N) cursor[idx] = 0;
}

// ---------------------------------------------------------------------------
// Fused projections (round-4 verified structure, static partition).
// Race-free: s1 cancels by softmax shift-invariance; s2[j] deferred to
// aggregate -> edge path depends only on prep outputs.
//
// NEW vs round-4: edge B is stored FRAGMENT-LINEAR in LDS.
//   B_lin[fi][lane] (fi = ct*4+kc, 16 B per lane) = ewT[ct*16+(lane&15)]
//                                                   [kc*32+(lane>>4)*8 .. +8)
// Every ds_read_b128 reads a contiguous 1 KB block -> <=2-way bank aliasing
// (free, m136), replacing the 8-way conflict of the [256][136] row-major
// layout (row stride 68 words == 4 mod 32 -> (l+q)%8 classes collide, 2.94x).
// Edge loop was LDS-pipe-bound: ~78 chunks/CU x 64 reads x 12cyc = ~25us
// baseline, ~73us with conflicts (matches round-6 counters: 5.46M conflict
// cycles, MfmaUtil 6%, VALUBusy 9%).
// ---------------------------------------------------------------------------
__global__ __launch_bounds__(512, 4) void proj_fused(
        const float* __restrict__ nf, const bf16_t* __restrict__ wT,
        const float* __restrict__ wb, const float* __restrict__ aW,
        bf16_t* __restrict__ h, float* __restrict__ s2,
        const float* __restrict__ ef, const bf16_t* __restrict__ ewT,
        const float* __restrict__ eb, const float* __restrict__ ab,
        const int* __restrict__ tgt, const int* __restrict__ nbr,
        int* __restrict__ cursor, float2* __restrict__ pairs,
        int N, int E, int NB_NODE, int EP_BLOCKS) {
    __shared__ __align__(16) unsigned char smem[71680];

    const int tid = threadIdx.x;
    const int wave = tid >> 6, lane = tid & 63;
    const int q = lane >> 4, l = lane & 15;

    if (blockIdx.x < NB_NODE) {
        // ------------------------- node path -------------------------
        bf16_t (*A)[264] = (bf16_t(*)[264])smem;                 // 67584 B
        float (*p2)[64] = (float(*)[64])(smem + 67584);          // 2048 B

        const int m0 = blockIdx.x * 128;
        for (int i = tid; i < 128 * 64; i += 512) {
            int r = i >> 6;
            int c4 = (i & 63) * 4;
            int row = m0 + r;
            if (row >= N) row = N - 1;
            const float4 v = *(const float4*)(nf + (size_t)row * 256 + c4);
            bf16_t* dst = &A[r][c4];
            dst[0] = (bf16_t)v.x; dst[1] = (bf16_t)v.y; dst[2] = (bf16_t)v.z; dst[3] = (bf16_t)v.w;
        }
        __syncthreads();

        const int rh = wave >> 2;   // row half (0/1)
        const int wc = wave & 3;    // col group

        f32x4 acc[4][4];
        for (int rt = 0; rt < 4; rt++)
            for (int ct = 0; ct < 4; ct++)
                acc[rt][ct] = (f32x4){0.f, 0.f, 0.f, 0.f};

        for (int kc = 0; kc < 8; kc++) {
            bf16x8 bf[4];
            for (int ct = 0; ct < 4; ct++) {
                int n = wc * 64 + ct * 16 + l;
                bf[ct] = *(const bf16x8*)(wT + (size_t)n * 256 + kc * 32 + q * 8);
            }
            bf16x8 af[4];
            for (int rt = 0; rt < 4; rt++)
                af[rt] = *(const bf16x8*)(&A[rh * 64 + rt * 16 + l][kc * 32 + q * 8]);
            for (int rt = 0; rt < 4; rt++)
                for (int ct = 0; ct < 4; ct++)
                    acc[rt][ct] = __builtin_amdgcn_mfma_f32_16x16x32_bf16(af[rt], bf[ct], acc[rt][ct], 0, 0, 0);
        }

        float bias[4], w2[4];
        for (int ct = 0; ct < 4; ct++) {
            int n = wc * 64 + ct * 16 + l;
            bias[ct] = wb[n];
            w2[ct] = aW[256 + n];
        }
        for (int rt = 0; rt < 4; rt++) {
            float rs2[4] = {0.f, 0.f, 0.f, 0.f};
            for (int ct = 0; ct < 4; ct++) {
                int col = wc * 64 + ct * 16 + l;
                for (int r = 0; r < 4; r++) {
                    float p = lrelu(acc[rt][ct][r] + bias[ct]);
                    int row = m0 + rh * 64 + rt * 16 + q * 4 + r;
                    if (row < N) h[(size_t)row * 256 + col] = (bf16_t)p;
                    rs2[r] += p * w2[ct];
                }
            }
            for (int off = 1; off < 16; off <<= 1)
                for (int r = 0; r < 4; r++)
                    rs2[r] += __shfl_xor(rs2[r], off, 64);
            if (l == 0)
                for (int r = 0; r < 4; r++)
                    p2[wave][rt * 16 + q * 4 + r] = rs2[r];
        }
        __syncthreads();
        if (tid < 128 && m0 + tid < N) {
            int rh2 = tid >> 6, t = tid & 63;
            s2[m0 + tid] = p2[rh2 * 4 + 0][t] + p2[rh2 * 4 + 1][t] + p2[rh2 * 4 + 2][t] + p2[rh2 * 4 + 3][t];
        }
        return;
    }

    // ------------------------- edge path -------------------------
    // Fragment-linear B: 64 fragments (ct*4+kc) x 64 lanes x 16 B = 64 KiB.
    bf16_t* Blin = (bf16_t*)smem;                                // 65536 B
    float2* EW = (float2*)(smem + 65536);                        // 2048 B

    {
        // stage: thread g = it*512+tid owns fragment-linear chunk g (16 B).
        // g = fi*64 + lane8; fi = ct*4+kc. Writes are linear -> conflict-free.
#pragma unroll
        for (int it = 0; it < 8; it++) {
            int g = it * 512 + tid;
            int fi = g >> 6, ln = g & 63;
            int ct = fi >> 2, kc = fi & 3;
            int sl = ln & 15, sq = ln >> 4;
            const bf16x8 v = *(const bf16x8*)(ewT + (size_t)(ct * 16 + sl) * 128 + kc * 32 + sq * 8);
            *(bf16x8*)(Blin + (size_t)g * 8) = v;
        }
    }
    if (tid < 256) EW[tid] = make_float2(eb[tid], aW[512 + tid]);
    const float ab0 = ab[0];
    __syncthreads();

    const int nchunks = (E + 15) >> 4;
    const int wstride = EP_BLOCKS * 8;
    int c = (blockIdx.x - NB_NODE) * 8 + wave;

    f32x4 a0[4], a1[4];
    if (c < nchunks) {
        int row = c * 16 + l;
        if (row >= E) row = E - 1;
        const float* arow = ef + (size_t)row * 128 + q * 8;
#pragma unroll
        for (int kc = 0; kc < 4; kc++) {
            a0[kc] = *(const f32x4*)(arow + kc * 32);
            a1[kc] = *(const f32x4*)(arow + kc * 32 + 4);
        }
    }

    while (c < nchunks) {
        const int e0 = c * 16;
        const int cn = c + wstride;

        bf16x8 af[4];
#pragma unroll
        for (int kc = 0; kc < 4; kc++) {
            af[kc][0] = (bf16_t)a0[kc][0]; af[kc][1] = (bf16_t)a0[kc][1];
            af[kc][2] = (bf16_t)a0[kc][2]; af[kc][3] = (bf16_t)a0[kc][3];
            af[kc][4] = (bf16_t)a1[kc][0]; af[kc][5] = (bf16_t)a1[kc][1];
            af[kc][6] = (bf16_t)a1[kc][2]; af[kc][7] = (bf16_t)a1[kc][3];
        }
        if (cn < nchunks) {
            int row = cn * 16 + l;
            if (row >= E) row = E - 1;
            const float* arow = ef + (size_t)row * 128 + q * 8;
#pragma unroll
            for (int kc = 0; kc < 4; kc++) {
                a0[kc] = *(const f32x4*)(arow + kc * 32);
                a1[kc] = *(const f32x4*)(arow + kc * 32 + 4);
            }
        }

        float rs0 = 0.f, rs1 = 0.f, rs2 = 0.f, rs3 = 0.f;
#pragma unroll 1
        for (int half = 0; half < 2; half++) {
            f32x4 acc[8];
#pragma unroll
            for (int t = 0; t < 8; t++) acc[t] = (f32x4){0.f, 0.f, 0.f, 0.f};
            __builtin_amdgcn_s_setprio(1);
#pragma unroll
            for (int kc = 0; kc < 4; kc++) {
#pragma unroll
                for (int t = 0; t < 8; t++) {
                    int ct = half * 8 + t;
                    // fragment-linear read: contiguous 1 KB across the wave
                    bf16x8 bf = *(const bf16x8*)(Blin + (size_t)((ct * 4 + kc) * 64 + lane) * 8);
                    acc[t] = __builtin_amdgcn_mfma_f32_16x16x32_bf16(af[kc], bf, acc[t], 0, 0, 0);
                }
            }
            __builtin_amdgcn_s_setprio(0);
#pragma unroll
            for (int t = 0; t < 8; t++) {
                int ct = half * 8 + t;
                float2 bw = EW[ct * 16 + l];
                rs0 += lrelu(acc[t][0] + bw.x) * bw.y;
                rs1 += lrelu(acc[t][1] + bw.x) * bw.y;
                rs2 += lrelu(acc[t][2] + bw.x) * bw.y;
                rs3 += lrelu(acc[t][3] + bw.x) * bw.y;
            }
        }
#pragma unroll
        for (int off = 1; off < 16; off <<= 1) {
            rs0 += __shfl_xor(rs0, off, 64);
            rs1 += __shfl_xor(rs1, off, 64);
            rs2 += __shfl_xor(rs2, off, 64);
            rs3 += __shfl_xor(rs3, off, 64);
        }
        // fused fill: lanes l<4 each own edge e0 + q*4 + l. pairs = {nbr, s3}
        if (l < 4) {
            int e = e0 + q * 4 + l;
            if (e < E) {
                float rsv = (l == 0) ? rs0 : (l == 1) ? rs1 : (l == 2) ? rs2 : rs3;
                int t = tgt[e];
                int j = nbr[e];
                int p = atomicAdd(&cursor[t], 1);
                if (p < CAP) {
                    float2 pr;
                    pr.x = __int_as_float(j);
                    pr.y = rsv + ab0;
                    pairs[(size_t)t * CAP + p] = pr;
                }
            }
        }
        c = cn;
    }
}

// ---------------------------------------------------------------------------
// Aggregate: one WAVE per node. Pairs {j, s3} preloaded into 2 regs/lane
// (coalesced); logit = s3 + s2[j] built in-register (s2 gather: 2 per lane,
// 40 KB L2-hot table). Max and exp-sum via butterfly shuffles; gather loop
// broadcasts {j, alpha} from registers via __shfl.
// ---------------------------------------------------------------------------
__global__ __launch_bounds__(256) void aggregate(const int* __restrict__ cursor,
                                                 const float2* __restrict__ pairs,
                                                 const float* __restrict__ s2,
                                                 const bf16_t* __restrict__ h,
                                                 float* __restrict__ out, int N) {
    const int wave = threadIdx.x >> 6, lane = threadIdx.x & 63;
    const int n = blockIdx.x * 4 + wave;
    if (n >= N) return;

    int deg = __builtin_amdgcn_readfirstlane(cursor[n]);
    if (deg > CAP) deg = CAP;
    const float2* pp = pairs + (size_t)n * CAP;

    // preload up to 2 pairs per lane (coalesced 512B loads) + s2[j] fold-in
    float2 pr0 = make_float2(0.f, 0.f);
    float2 pr1 = make_float2(0.f, 0.f);
    if (lane < deg) pr0 = pp[lane];
    if (lane + 64 < deg) pr1 = pp[lane + 64];
    float lg0 = (lane < deg) ? pr0.y + s2[__float_as_int(pr0.x)] : -1e30f;
    float lg1 = (lane + 64 < deg) ? pr1.y + s2[__float_as_int(pr1.x)] : -1e30f;

    // in-register segment max
    float m = fmaxf(lg0, lg1);
#pragma unroll
    for (int off = 32; off > 0; off >>= 1) m = fmaxf(m, __shfl_xor(m, off, 64));

    // in-register exp + sum
    float ex0 = (lane < deg) ? expf(lg0 - m) : 0.f;
    float ex1 = (lane + 64 < deg) ? expf(lg1 - m) : 0.f;
    float s = ex0 + ex1;
#pragma unroll
    for (int off = 32; off > 0; off >>= 1) s += __shfl_xor(s, off, 64);
    const float inv = (deg > 0 && s > 0.f) ? 1.0f / s : 0.f;

    // gather: out[n][lane*4..+4) = sum_i alpha_i * h[j_i][lane*4..+4)
    f32x4 acc = (f32x4){0.f, 0.f, 0.f, 0.f};
    const bf16_t* hf = h + lane * 4;
    const int d0 = deg < 64 ? deg : 64;
#pragma unroll 4
    for (int i = 0; i < d0; i++) {
        float a = __shfl(ex0, i, 64);
        int j = __float_as_int(__shfl(pr0.x, i, 64));
        bf16x4 v = *(const bf16x4*)(hf + (size_t)j * 256);
        acc[0] += a * (float)v[0];
        acc[1] += a * (float)v[1];
        acc[2] += a * (float)v[2];
        acc[3] += a * (float)v[3];
    }
#pragma unroll 4
    for (int i = 64; i < deg; i++) {
        float a = __shfl(ex1, i - 64, 64);
        int j = __float_as_int(__shfl(pr1.x, i - 64, 64));
        bf16x4 v = *(const bf16x4*)(hf + (size_t)j * 256);
        acc[0] += a * (float)v[0];
        acc[1] += a * (float)v[1];
        acc[2] += a * (float)v[2];
        acc[3] += a * (float)v[3];
    }
    float4 o;
    o.x = lrelu(acc[0] * inv);
    o.y = lrelu(acc[1] * inv);
    o.z = lrelu(acc[2] * inv);
    o.w = lrelu(acc[3] * inv);
    *(float4*)(out + (size_t)n * 256 + lane * 4) = o;
}

// ---------------------------------------------------------------------------
extern "C" void kernel_launch(void* const* d_in, const int* in_sizes, int n_in,
                              void* d_out, int out_size, void* d_ws, size_t ws_size,
                              hipStream_t stream) {
    const float* nf  = (const float*)d_in[0];
    const float* ef  = (const float*)d_in[1];
    const int*  eidx = (const int*)d_in[2];
    const float* wW  = (const float*)d_in[3];
    const float* wb  = (const float*)d_in[4];
    const float* ewW = (const float*)d_in[5];
    const float* ewb = (const float*)d_in[6];
    const float* aW  = (const float*)d_in[7];
    const float* ab  = (const float*)d_in[8];
    float* out = (float*)d_out;

    const int N = in_sizes[0] / DH;   // 10000
    const int E = in_sizes[1] / DE;   // 320000
    const int* tgt = eidx;
    const int* nbr = eidx + E;

    char* ws = (char*)d_ws;
    size_t off = 0;
    auto alloc = [&](size_t bytes) -> void* {
        void* p = ws + off;
        off += (bytes + 255) & ~(size_t)255;
        return p;
    };
    bf16_t* wT      = (bf16_t*)alloc((size_t)256 * 256 * 2);
    bf16_t* ewT     = (bf16_t*)alloc((size_t)256 * 128 * 2);
    bf16_t* h       = (bf16_t*)alloc((size_t)N * 256 * 2);
    float*  s2      = (float*)alloc((size_t)N * 4);
    int*    cursor  = (int*)alloc((size_t)N * 4);
    float2* pairs   = (float2*)alloc((size_t)N * CAP * 8);

    prep_weights<<<256, 256, 0, stream>>>(wW, ewW, wT, ewT, cursor, N);

    const int NB_NODE = (N + 127) / 128;          // 79
    const int EP_BLOCKS = 512 - NB_NODE;          // 433 -> total grid 512 = 2/CU
    proj_fused<<<NB_NODE + EP_BLOCKS, 512, 0, stream>>>(
        nf, wT, wb, aW, h, s2,
        ef, ewT, ewb, ab, tgt, nbr, cursor, pairs,
        N, E, NB_NODE, EP_BLOCKS);

    aggregate<<<(N + 3) / 4, 256, 0, stream>>>(cursor, pairs, s2, h, out, N);
}

// Round 8
// 295.043 us; speedup vs baseline: 1.1994x; 1.0166x over previous
//
#include <hip/hip_runtime.h>
#include <hip/hip_bf16.h>

#define SLOPE 0.2f
#define DH 256
#define DE 128
#define CAP 128   // max edges per node slot; Binomial(320k,1e-4) max ~56, 128 is ~17 sigma

typedef __bf16 bf16_t;
typedef bf16_t bf16x8 __attribute__((ext_vector_type(8)));
typedef bf16_t bf16x4 __attribute__((ext_vector_type(4)));
typedef float f32x4 __attribute__((ext_vector_type(4)));

__device__ __forceinline__ float lrelu(float x) { return x > 0.f ? x : SLOPE * x; }

// ---------------------------------------------------------------------------
// Cast + transpose weights to bf16: wT[n][k] = wW[k][n]  (256x256)
//                                   ewT[n][k] = ewW[k][n] (256x128)
// Also zeroes the per-node edge-slot cursor.
// ---------------------------------------------------------------------------
__global__ void prep_weights(const float* __restrict__ wW, const float* __restrict__ ewW,
                             bf16_t* __restrict__ wT, bf16_t* __restrict__ ewT,
                             int* __restrict__ cursor, int N) {
    int n = blockIdx.x;   // 0..255 (output col of original)
    int k = threadIdx.x;  // 0..255
    wT[n * 256 + k] = (bf16_t)wW[k * 256 + n];
    if (k < 128) ewT[n * 128 + k] = (bf16_t)ewW[k * 256 + n];
    int idx = blockIdx.x * 256 + threadIdx.x;
    if (idx < N) cursor[idx] = 0;
}

// ---------------------------------------------------------------------------
// Fused projections. Race-free: s1 cancels by softmax shift-invariance;
// s2[j] deferred to aggregate -> edge path depends only on prep outputs.
//
// NEW vs round-7: node blocks FALL THROUGH into the edge loop after their
// node path (no idle 15% of the machine for the back half of the kernel).
// Static tail split: edge blocks cover chunks [0, CMAIN), node blocks cover
// [CMAIN, nchunks) at ~2 chunks/wave — sized to their late start. No atomic
// dispenser (round-6 lesson: dependent same-line atomics serialize).
//
// Edge B stays FRAGMENT-LINEAR in LDS (<=2-way bank aliasing, free).
// ---------------------------------------------------------------------------
__global__ __launch_bounds__(512, 4) void proj_fused(
        const float* __restrict__ nf, const bf16_t* __restrict__ wT,
        const float* __restrict__ wb, const float* __restrict__ aW,
        bf16_t* __restrict__ h, float* __restrict__ s2,
        const float* __restrict__ ef, const bf16_t* __restrict__ ewT,
        const float* __restrict__ eb, const float* __restrict__ ab,
        const int* __restrict__ tgt, const int* __restrict__ nbr,
        int* __restrict__ cursor, float2* __restrict__ pairs,
        int N, int E, int NB_NODE, int EP_BLOCKS) {
    __shared__ __align__(16) unsigned char smem[71680];

    const int tid = threadIdx.x;
    const int wave = tid >> 6, lane = tid & 63;
    const int q = lane >> 4, l = lane & 15;

    const int nchunks = (E + 15) >> 4;
    int cmain = nchunks - 2 * (NB_NODE * 8);   // tail reserved for node blocks
    if (cmain < 0) cmain = 0;

    int c0, cstep, cend;

    if (blockIdx.x < NB_NODE) {
        // ------------------------- node path -------------------------
        bf16_t (*A)[264] = (bf16_t(*)[264])smem;                 // 67584 B
        float (*p2)[64] = (float(*)[64])(smem + 67584);          // 2048 B

        const int m0 = blockIdx.x * 128;
        for (int i = tid; i < 128 * 64; i += 512) {
            int r = i >> 6;
            int c4 = (i & 63) * 4;
            int row = m0 + r;
            if (row >= N) row = N - 1;
            const float4 v = *(const float4*)(nf + (size_t)row * 256 + c4);
            bf16_t* dst = &A[r][c4];
            dst[0] = (bf16_t)v.x; dst[1] = (bf16_t)v.y; dst[2] = (bf16_t)v.z; dst[3] = (bf16_t)v.w;
        }
        __syncthreads();

        const int rh = wave >> 2;   // row half (0/1)
        const int wc = wave & 3;    // col group

        f32x4 acc[4][4];
        for (int rt = 0; rt < 4; rt++)
            for (int ct = 0; ct < 4; ct++)
                acc[rt][ct] = (f32x4){0.f, 0.f, 0.f, 0.f};

        for (int kc = 0; kc < 8; kc++) {
            bf16x8 bf[4];
            for (int ct = 0; ct < 4; ct++) {
                int n = wc * 64 + ct * 16 + l;
                bf[ct] = *(const bf16x8*)(wT + (size_t)n * 256 + kc * 32 + q * 8);
            }
            bf16x8 af[4];
            for (int rt = 0; rt < 4; rt++)
                af[rt] = *(const bf16x8*)(&A[rh * 64 + rt * 16 + l][kc * 32 + q * 8]);
            for (int rt = 0; rt < 4; rt++)
                for (int ct = 0; ct < 4; ct++)
                    acc[rt][ct] = __builtin_amdgcn_mfma_f32_16x16x32_bf16(af[rt], bf[ct], acc[rt][ct], 0, 0, 0);
        }

        float bias[4], w2[4];
        for (int ct = 0; ct < 4; ct++) {
            int n = wc * 64 + ct * 16 + l;
            bias[ct] = wb[n];
            w2[ct] = aW[256 + n];
        }
        for (int rt = 0; rt < 4; rt++) {
            float rs2[4] = {0.f, 0.f, 0.f, 0.f};
            for (int ct = 0; ct < 4; ct++) {
                int col = wc * 64 + ct * 16 + l;
                for (int r = 0; r < 4; r++) {
                    float p = lrelu(acc[rt][ct][r] + bias[ct]);
                    int row = m0 + rh * 64 + rt * 16 + q * 4 + r;
                    if (row < N) h[(size_t)row * 256 + col] = (bf16_t)p;
                    rs2[r] += p * w2[ct];
                }
            }
            for (int off = 1; off < 16; off <<= 1)
                for (int r = 0; r < 4; r++)
                    rs2[r] += __shfl_xor(rs2[r], off, 64);
            if (l == 0)
                for (int r = 0; r < 4; r++)
                    p2[wave][rt * 16 + q * 4 + r] = rs2[r];
        }
        __syncthreads();
        if (tid < 128 && m0 + tid < N) {
            int rh2 = tid >> 6, t = tid & 63;
            s2[m0 + tid] = p2[rh2 * 4 + 0][t] + p2[rh2 * 4 + 1][t] + p2[rh2 * 4 + 2][t] + p2[rh2 * 4 + 3][t];
        }
        __syncthreads();   // A and p2 fully consumed before LDS restaged as Blin

        // tail share of edge work: 2 chunks per wave, starting at cmain
        c0 = cmain + blockIdx.x * 8 + wave;
        cstep = NB_NODE * 8;
        cend = nchunks;
    } else {
        c0 = (blockIdx.x - NB_NODE) * 8 + wave;
        cstep = EP_BLOCKS * 8;
        cend = cmain;
    }

    // ------------------------- edge path (all blocks) -------------------------
    // Fragment-linear B: 64 fragments (ct*4+kc) x 64 lanes x 16 B = 64 KiB.
    bf16_t* Blin = (bf16_t*)smem;                                // 65536 B
    float2* EW = (float2*)(smem + 65536);                        // 2048 B

    {
        // stage: thread g = it*512+tid owns fragment-linear chunk g (16 B).
#pragma unroll
        for (int it = 0; it < 8; it++) {
            int g = it * 512 + tid;
            int fi = g >> 6, ln = g & 63;
            int ct = fi >> 2, kc = fi & 3;
            int sl = ln & 15, sq = ln >> 4;
            const bf16x8 v = *(const bf16x8*)(ewT + (size_t)(ct * 16 + sl) * 128 + kc * 32 + sq * 8);
            *(bf16x8*)(Blin + (size_t)g * 8) = v;
        }
    }
    if (tid < 256) EW[tid] = make_float2(eb[tid], aW[512 + tid]);
    const float ab0 = ab[0];
    __syncthreads();

    int c = c0;

    f32x4 a0[4], a1[4];
    if (c < cend) {
        int row = c * 16 + l;
        if (row >= E) row = E - 1;
        const float* arow = ef + (size_t)row * 128 + q * 8;
#pragma unroll
        for (int kc = 0; kc < 4; kc++) {
            a0[kc] = *(const f32x4*)(arow + kc * 32);
            a1[kc] = *(const f32x4*)(arow + kc * 32 + 4);
        }
    }

    while (c < cend) {
        const int e0 = c * 16;
        const int cn = c + cstep;

        bf16x8 af[4];
#pragma unroll
        for (int kc = 0; kc < 4; kc++) {
            af[kc][0] = (bf16_t)a0[kc][0]; af[kc][1] = (bf16_t)a0[kc][1];
            af[kc][2] = (bf16_t)a0[kc][2]; af[kc][3] = (bf16_t)a0[kc][3];
            af[kc][4] = (bf16_t)a1[kc][0]; af[kc][5] = (bf16_t)a1[kc][1];
            af[kc][6] = (bf16_t)a1[kc][2]; af[kc][7] = (bf16_t)a1[kc][3];
        }
        if (cn < cend) {
            int row = cn * 16 + l;
            if (row >= E) row = E - 1;
            const float* arow = ef + (size_t)row * 128 + q * 8;
#pragma unroll
            for (int kc = 0; kc < 4; kc++) {
                a0[kc] = *(const f32x4*)(arow + kc * 32);
                a1[kc] = *(const f32x4*)(arow + kc * 32 + 4);
            }
        }

        float rs0 = 0.f, rs1 = 0.f, rs2 = 0.f, rs3 = 0.f;
#pragma unroll 1
        for (int half = 0; half < 2; half++) {
            f32x4 acc[8];
#pragma unroll
            for (int t = 0; t < 8; t++) acc[t] = (f32x4){0.f, 0.f, 0.f, 0.f};
            __builtin_amdgcn_s_setprio(1);
#pragma unroll
            for (int kc = 0; kc < 4; kc++) {
#pragma unroll
                for (int t = 0; t < 8; t++) {
                    int ct = half * 8 + t;
                    // fragment-linear read: contiguous 1 KB across the wave
                    bf16x8 bf = *(const bf16x8*)(Blin + (size_t)((ct * 4 + kc) * 64 + lane) * 8);
                    acc[t] = __builtin_amdgcn_mfma_f32_16x16x32_bf16(af[kc], bf, acc[t], 0, 0, 0);
                }
            }
            __builtin_amdgcn_s_setprio(0);
#pragma unroll
            for (int t = 0; t < 8; t++) {
                int ct = half * 8 + t;
                float2 bw = EW[ct * 16 + l];
                rs0 += lrelu(acc[t][0] + bw.x) * bw.y;
                rs1 += lrelu(acc[t][1] + bw.x) * bw.y;
                rs2 += lrelu(acc[t][2] + bw.x) * bw.y;
                rs3 += lrelu(acc[t][3] + bw.x) * bw.y;
            }
        }
#pragma unroll
        for (int off = 1; off < 16; off <<= 1) {
            rs0 += __shfl_xor(rs0, off, 64);
            rs1 += __shfl_xor(rs1, off, 64);
            rs2 += __shfl_xor(rs2, off, 64);
            rs3 += __shfl_xor(rs3, off, 64);
        }
        // fused fill: lanes l<4 each own edge e0 + q*4 + l. pairs = {nbr, s3}
        if (l < 4) {
            int e = e0 + q * 4 + l;
            if (e < E) {
                float rsv = (l == 0) ? rs0 : (l == 1) ? rs1 : (l == 2) ? rs2 : rs3;
                int t = tgt[e];
                int j = nbr[e];
                int p = atomicAdd(&cursor[t], 1);
                if (p < CAP) {
                    float2 pr;
                    pr.x = __int_as_float(j);
                    pr.y = rsv + ab0;
                    pairs[(size_t)t * CAP + p] = pr;
                }
            }
        }
        c = cn;
    }
}

// ---------------------------------------------------------------------------
// Aggregate: one WAVE per node. Pairs {j, s3} preloaded into 2 regs/lane
// (coalesced); logit = s3 + s2[j] in-register. Max/exp-sum via butterfly
// shuffles; gather loop broadcasts {j, alpha} from regs via __shfl.
// unroll 8: more independent L2 gathers in flight (loop is latency-bound;
// only dependence across iterations is the 4-FMA accumulate).
// ---------------------------------------------------------------------------
__global__ __launch_bounds__(256) void aggregate(const int* __restrict__ cursor,
                                                 const float2* __restrict__ pairs,
                                                 const float* __restrict__ s2,
                                                 const bf16_t* __restrict__ h,
                                                 float* __restrict__ out, int N) {
    const int wave = threadIdx.x >> 6, lane = threadIdx.x & 63;
    const int n = blockIdx.x * 4 + wave;
    if (n >= N) return;

    int deg = __builtin_amdgcn_readfirstlane(cursor[n]);
    if (deg > CAP) deg = CAP;
    const float2* pp = pairs + (size_t)n * CAP;

    // preload up to 2 pairs per lane (coalesced 512B loads) + s2[j] fold-in
    float2 pr0 = make_float2(0.f, 0.f);
    float2 pr1 = make_float2(0.f, 0.f);
    if (lane < deg) pr0 = pp[lane];
    if (lane + 64 < deg) pr1 = pp[lane + 64];
    float lg0 = (lane < deg) ? pr0.y + s2[__float_as_int(pr0.x)] : -1e30f;
    float lg1 = (lane + 64 < deg) ? pr1.y + s2[__float_as_int(pr1.x)] : -1e30f;

    // in-register segment max
    float m = fmaxf(lg0, lg1);
#pragma unroll
    for (int off = 32; off > 0; off >>= 1) m = fmaxf(m, __shfl_xor(m, off, 64));

    // in-register exp + sum
    float ex0 = (lane < deg) ? expf(lg0 - m) : 0.f;
    float ex1 = (lane + 64 < deg) ? expf(lg1 - m) : 0.f;
    float s = ex0 + ex1;
#pragma unroll
    for (int off = 32; off > 0; off >>= 1) s += __shfl_xor(s, off, 64);
    const float inv = (deg > 0 && s > 0.f) ? 1.0f / s : 0.f;

    // gather: out[n][lane*4..+4) = sum_i alpha_i * h[j_i][lane*4..+4)
    f32x4 acc = (f32x4){0.f, 0.f, 0.f, 0.f};
    const bf16_t* hf = h + lane * 4;
    const int d0 = deg < 64 ? deg : 64;
#pragma unroll 8
    for (int i = 0; i < d0; i++) {
        float a = __shfl(ex0, i, 64);
        int j = __float_as_int(__shfl(pr0.x, i, 64));
        bf16x4 v = *(const bf16x4*)(hf + (size_t)j * 256);
        acc[0] += a * (float)v[0];
        acc[1] += a * (float)v[1];
        acc[2] += a * (float)v[2];
        acc[3] += a * (float)v[3];
    }
#pragma unroll 4
    for (int i = 64; i < deg; i++) {
        float a = __shfl(ex1, i - 64, 64);
        int j = __float_as_int(__shfl(pr1.x, i - 64, 64));
        bf16x4 v = *(const bf16x4*)(hf + (size_t)j * 256);
        acc[0] += a * (float)v[0];
        acc[1] += a * (float)v[1];
        acc[2] += a * (float)v[2];
        acc[3] += a * (float)v[3];
    }
    float4 o;
    o.x = lrelu(acc[0] * inv);
    o.y = lrelu(acc[1] * inv);
    o.z = lrelu(acc[2] * inv);
    o.w = lrelu(acc[3] * inv);
    *(float4*)(out + (size_t)n * 256 + lane * 4) = o;
}

// ---------------------------------------------------------------------------
extern "C" void kernel_launch(void* const* d_in, const int* in_sizes, int n_in,
                              void* d_out, int out_size, void* d_ws, size_t ws_size,
                              hipStream_t stream) {
    const float* nf  = (const float*)d_in[0];
    const float* ef  = (const float*)d_in[1];
    const int*  eidx = (const int*)d_in[2];
    const float* wW  = (const float*)d_in[3];
    const float* wb  = (const float*)d_in[4];
    const float* ewW = (const float*)d_in[5];
    const float* ewb = (const float*)d_in[6];
    const float* aW  = (const float*)d_in[7];
    const float* ab  = (const float*)d_in[8];
    float* out = (float*)d_out;

    const int N = in_sizes[0] / DH;   // 10000
    const int E = in_sizes[1] / DE;   // 320000
    const int* tgt = eidx;
    const int* nbr = eidx + E;

    char* ws = (char*)d_ws;
    size_t off = 0;
    auto alloc = [&](size_t bytes) -> void* {
        void* p = ws + off;
        off += (bytes + 255) & ~(size_t)255;
        return p;
    };
    bf16_t* wT      = (bf16_t*)alloc((size_t)256 * 256 * 2);
    bf16_t* ewT     = (bf16_t*)alloc((size_t)256 * 128 * 2);
    bf16_t* h       = (bf16_t*)alloc((size_t)N * 256 * 2);
    float*  s2      = (float*)alloc((size_t)N * 4);
    int*    cursor  = (int*)alloc((size_t)N * 4);
    float2* pairs   = (float2*)alloc((size_t)N * CAP * 8);

    prep_weights<<<256, 256, 0, stream>>>(wW, ewW, wT, ewT, cursor, N);

    const int NB_NODE = (N + 127) / 128;          // 79
    const int EP_BLOCKS = 512 - NB_NODE;          // 433 -> total grid 512 = 2/CU
    proj_fused<<<NB_NODE + EP_BLOCKS, 512, 0, stream>>>(
        nf, wT, wb, aW, h, s2,
        ef, ewT, ewb, ab, tgt, nbr, cursor, pairs,
        N, E, NB_NODE, EP_BLOCKS);

    aggregate<<<(N + 3) / 4, 256, 0, stream>>>(cursor, pairs, s2, h, out, N);
}